// Round 15
// baseline (350.021 us; speedup 1.0000x reference)
//
#include <hip/hip_runtime.h>
#include <hip/hip_fp16.h>

#define HDIM 64
#define NEG_SLOPE 0.01f
#define CAPB 8192      // bucketed[] region per 128-node bucket
#define BCAP 6144      // LDS staging capacity in k_csr
#define EPB  4096      // edges per k_bucket block

typedef _Float16 half8 __attribute__((ext_vector_type(8)));
typedef float f32x4 __attribute__((ext_vector_type(4)));

static __device__ __forceinline__ float h_lo(unsigned d) {
    return __half2float(__ushort_as_half((unsigned short)(d & 0xffffu)));
}
static __device__ __forceinline__ float h_hi(unsigned d) {
    return __half2float(__ushort_as_half((unsigned short)(d >> 16)));
}
static __device__ __forceinline__ unsigned packh(float a, float b) {
    unsigned short ra = __half_as_ushort(__float2half(a));
    unsigned short rb = __half_as_ushort(__float2half(b));
    return ((unsigned)rb << 16) | (unsigned)ra;
}
static __device__ __forceinline__ half8 u4h(uint4 v) {
    union { uint4 u; half8 h; } x; x.u = v; return x.h;
}
static __device__ __forceinline__ __half2 uh2(unsigned u) {
    union { unsigned u; __half2 h; } x; x.u = u; return x.h;
}
// async global->LDS: per-lane global src, wave-uniform LDS base (+lane*16B)
static __device__ __forceinline__ void dma16(const unsigned* gsrc, unsigned* ldst) {
    __builtin_amdgcn_global_load_lds(
        (const __attribute__((address_space(1))) unsigned*)gsrc,
        (__attribute__((address_space(3))) unsigned*)ldst, 16, 0, 0);
}

// merged setup: WTh prep + gcur init + sentinel rows (features and t)
__global__ void k_setup(int ptotal, const float* __restrict__ W_mid,
                        unsigned short* __restrict__ WTh,
                        int NB, int* gcur, int N, unsigned* xAP, unsigned* xBP,
                        float* tvec) {
    int i = blockIdx.x * blockDim.x + threadIdx.x;
    if (i < ptotal) {
        int l = i >> 13;
        int rem = i & 8191;
        int h = rem >> 7;
        int k = rem & 127;
        const float* W = W_mid + (size_t)l * 129 * 64;
        float v = W[k * 64 + h] - ((k < 64) ? W[(64 + k) * 64 + h] : 0.f);
        WTh[i] = __half_as_ushort(__float2half(v));
    }
    if (i < NB) gcur[i] = i * CAPB;
    if (i < 32) xAP[(size_t)N * 32 + i] = 0u;
    else if (i < 64) xBP[(size_t)N * 32 + (i - 32)] = 0u;
    else if (i == 64) tvec[N] = 0.f;
}

// Phase 1: counting-sort bucketing. One atomic pass (rank+count), LDS scan,
// in-LDS sort by bucket, coalesced run-wise write-out.
__global__ __launch_bounds__(1024) void k_bucket(
        int E, const int* __restrict__ src, const int* __restrict__ dst,
        int* gcur, unsigned* __restrict__ bucketed, int NB) {
    __shared__ int lh[512];       // per-bucket counts (preserved)
    __shared__ int sd[512];       // inclusive scan
    __shared__ int lbase[512];    // global base per bucket
    __shared__ unsigned sorted[EPB];
    int t = threadIdx.x;
    int e0 = blockIdx.x * EPB;
    if (t < 512) lh[t] = 0;
    __syncthreads();
    int dv[4], sv[4], rv[4];
#pragma unroll
    for (int k = 0; k < 4; ++k) {
        int e = e0 + k * 1024 + t;
        dv[k] = (e < E) ? dst[e] : -1;
        sv[k] = (e < E) ? src[e] : 0;
    }
#pragma unroll
    for (int k = 0; k < 4; ++k)
        rv[k] = (dv[k] >= 0) ? atomicAdd(&lh[((unsigned)dv[k]) >> 7], 1) : 0;
    __syncthreads();
    int c = (t < 512) ? lh[t] : 0;
    if (t < 512) {
        lbase[t] = (c > 0) ? atomicAdd(&gcur[t], c) : 0;
        sd[t] = c;
    }
    __syncthreads();
    int x = c;
    for (int s = 1; s < 512; s <<= 1) {
        int p = (t < 512 && t >= s) ? sd[t - s] : 0;
        __syncthreads();
        if (t < 512) { x += p; sd[t] = x; }
        __syncthreads();
    }
    // place into bucket-sorted LDS order: idx = excl(b) + rank
#pragma unroll
    for (int k = 0; k < 4; ++k) {
        if (dv[k] >= 0) {
            int b = ((unsigned)dv[k]) >> 7;
            sorted[sd[b] - lh[b] + rv[k]] = ((unsigned)dv[k] << 16) | (unsigned)sv[k];
        }
    }
    __syncthreads();
    int ntot = sd[511];
    for (int i = t; i < ntot; i += 1024) {
        unsigned w = sorted[i];
        int b = (int)(w >> 23);                    // dst>>7
        int pos = lbase[b] + (i - (sd[b] - lh[b]));
        if (pos < (b + 1) * CAPB) bucketed[pos] = w;
    }
}

// Phase 2: per bucket, internal gstart scan + LDS hist/scan -> rowptr/ssinv,
// exact csr, LDS-built padded pcsr (coalesced dump), AND fused conv_in.
__global__ __launch_bounds__(512) void k_csr(
        int N, int NB, const unsigned* __restrict__ bucketed, const int* __restrict__ gcur,
        unsigned short* __restrict__ csr, unsigned short* __restrict__ pcsr,
        int* __restrict__ rowptr, float* __restrict__ ssinv,
        const float* __restrict__ x0, const float* __restrict__ W_in,
        const float* __restrict__ b_in, unsigned* __restrict__ xAP) {
    __shared__ unsigned st[BCAP];                 // 24 KB
    __shared__ unsigned short lpcsr[128 * 64];    // 16 KB node-major slots
    __shared__ int hist[128], cur[128], excl[128], sgp[128], sdegl[128];
    __shared__ float sssl[128];
    __shared__ int gsd[512];
    int b = blockIdx.x, t = threadIdx.x;
    int n0 = b << 7;
    int nn = min(128, N - n0);
    // internal exclusive scan of bucket counts -> base for this block
    int cc = (t < NB) ? min(gcur[t] - t * CAPB, CAPB) : 0;
    gsd[t] = cc;
    __syncthreads();
    int xs = cc;
    for (int s = 1; s < 512; s <<= 1) {
        int p = (t >= s) ? gsd[t - s] : 0;
        __syncthreads();
        xs += p;
        gsd[t] = xs;
        __syncthreads();
    }
    int cnt = min(gcur[b] - b * CAPB, CAPB);
    int base = gsd[b] - cnt;
    if (b == NB - 1 && t == 0) rowptr[N] = gsd[NB - 1];
    if (t < 128) { hist[t] = 0; sgp[t] = 0; }
    unsigned sent = ((unsigned)N << 16) | (unsigned)N;
    for (int i = t; i < 4096; i += 512) ((unsigned*)lpcsr)[i] = sent;
    __syncthreads();
    bool single = (cnt <= BCAP);
    for (int off = 0; off < cnt; off += BCAP) {
        int bs = min(BCAP, cnt - off);
        for (int i = t; i < bs; i += 512) {
            unsigned w = bucketed[b * CAPB + off + i];
            if (single) st[i] = w;
            int d = (int)(w >> 16);
            int s = (int)(w & 0xffffu);
            int dl = d - n0;
            atomicAdd(&hist[dl], 1);
            atomicAdd(&sgp[dl], ((s < d) ? 1024 : 0) + ((s == d) ? 1 : 0));
        }
    }
    __syncthreads();
    int deg_t = (t < 128) ? hist[t] : 0;
    int x = deg_t;
    for (int s = 1; s < 128; s <<= 1) {
        int p = (t < 128 && t >= s) ? hist[t - s] : 0;
        __syncthreads();
        if (t < 128) { x += p; hist[t] = x; }
        __syncthreads();
    }
    if (t < 128) {
        int ex = hist[t] - deg_t;
        excl[t] = ex;
        cur[t] = ex;
        sdegl[t] = deg_t;
        float ssv = 0.f;
        if (t < nn) {
            rowptr[n0 + t] = base + ex;
            int sg = sgp[t];
            int lt = sg >> 10, eq = sg & 1023;
            float ss = (float)(deg_t - eq - 2 * lt);
            ssv = (deg_t > 0) ? ss / (float)deg_t : 0.f;
            ssinv[n0 + t] = ssv;
        }
        sssl[t] = ssv;
    }
    __syncthreads();
    for (int off = 0; off < cnt; off += BCAP) {
        int bs = min(BCAP, cnt - off);
        if (!single) {
            for (int i = t; i < bs; i += 512) st[i] = bucketed[b * CAPB + off + i];
            __syncthreads();
        }
        for (int i = t; i < bs; i += 512) {
            unsigned w = st[i];
            int dl = (int)(w >> 16) - n0;
            unsigned short sval = (unsigned short)(w & 0xffffu);
            int p = atomicAdd(&cur[dl], 1);
            csr[base + p] = sval;
            int r = p - excl[dl];
            if (r < 64) lpcsr[(dl << 6) + r] = sval;
        }
        if (!single) __syncthreads();
    }
    __syncthreads();
    // coalesced dump of node-major slots -> global pcsr (16 KB contiguous)
    {
        uint4* gp = (uint4*)(pcsr + ((size_t)b << 13));
        const uint4* lp = (const uint4*)lpcsr;
        for (int i = t; i < 1024; i += 512) gp[i] = lp[i];
    }
    // fused conv_in: 8 waves x 16 nodes; x [N,1] fp32 -> packed fp16 row
    int lane = t & 63;
    int wvq = t >> 6;
    float w1 = W_in[lane], w2 = W_in[64 + lane], w3 = W_in[128 + lane];
    float bi = b_in[lane];
    for (int i = 0; i < 16; ++i) {
        int nd = (wvq << 4) + i;
        int node = n0 + nd;
        if (node >= N) break;
        int deg = sdegl[nd];
        float s;
        if (deg <= 64) {
            int sl = (int)lpcsr[(nd << 6) + lane];
            s = (sl < N) ? x0[sl] : 0.f;
        } else {
            s = 0.f;
            int bg = base + excl[nd], en = bg + deg;
            for (int e = bg + lane; e < en; e += 64) s += x0[csr[e]];
        }
        for (int m = 32; m >= 1; m >>= 1) s += __shfl_xor(s, m, 64);
        float invd = 1.f / (float)max(deg, 1);
        float mean = s * invd;
        float xi = x0[node];
        float y = xi * (w1 - w2) + mean * w2 + sssl[nd] * w3 + bi;
        if (deg == 0) y = 0.f;
        float ylo = __shfl(y, (2 * lane) & 63, 64);
        float yhi = __shfl(y, (2 * lane + 1) & 63, 64);
        if (lane < 32) xAP[(size_t)node * 32 + lane] = packh(ylo, yhi);
    }
}

// one 32-slot chunk: 4 shfl + 4 unguarded uint4 loads, fp16 packed accumulate
static __device__ __forceinline__ void chunk_acc(
        const uint4* __restrict__ xin16, int sv, int base, int sub, int lq,
        __half2& c0, __half2& c1, __half2& c2, __half2& c3) {
    int s0 = __shfl(sv, base + sub, 64);
    int s1 = __shfl(sv, base + 8 + sub, 64);
    int s2 = __shfl(sv, base + 16 + sub, 64);
    int s3 = __shfl(sv, base + 24 + sub, 64);
    uint4 d0 = xin16[(size_t)s0 * 8 + lq];
    uint4 d1 = xin16[(size_t)s1 * 8 + lq];
    uint4 d2 = xin16[(size_t)s2 * 8 + lq];
    uint4 d3 = xin16[(size_t)s3 * 8 + lq];
    c0 = __hadd2(c0, __hadd2(__hadd2(uh2(d0.x), uh2(d1.x)), __hadd2(uh2(d2.x), uh2(d3.x))));
    c1 = __hadd2(c1, __hadd2(__hadd2(uh2(d0.y), uh2(d1.y)), __hadd2(uh2(d2.y), uh2(d3.y))));
    c2 = __hadd2(c2, __hadd2(__hadd2(uh2(d0.z), uh2(d1.z)), __hadd2(uh2(d2.z), uh2(d3.z))));
    c3 = __hadd2(c3, __hadd2(__hadd2(uh2(d0.w), uh2(d1.w)), __hadd2(uh2(d2.w), uh2(d3.w))));
}

// rare exact-csr gather (deg>64), f32 accumulate, reduced into a[8]
static __device__ __forceinline__ void slow_gather(
        const uint4* __restrict__ xin16, const unsigned short* __restrict__ csr,
        int beg, int end, int N, int lane, int sub, int lq, float* a) {
#pragma unroll
    for (int j = 0; j < 8; ++j) a[j] = 0.f;
    for (int tb = beg; tb < end; tb += 64) {
        int cnt = min(64, end - tb);
        int sv = (lane < cnt) ? (int)csr[tb + lane] : N;
        int ng = (cnt + 7) >> 3;
        for (int g = 0; g < ng; ++g) {
            int si = __shfl(sv, (g << 3) + sub, 64);
            uint4 d = xin16[(size_t)si * 8 + lq];
            a[0] += h_lo(d.x); a[1] += h_hi(d.x);
            a[2] += h_lo(d.y); a[3] += h_hi(d.y);
            a[4] += h_lo(d.z); a[5] += h_hi(d.z);
            a[6] += h_lo(d.w); a[7] += h_hi(d.w);
        }
    }
#pragma unroll
    for (int m = 8; m <= 32; m <<= 1) {
#pragma unroll
        for (int j = 0; j < 8; ++j) a[j] += __shfl_xor(a[j], m, 64);
    }
}

// Fused layer: DMA-staged gather (global_load_lds -> 64KB LDS, no VGPR cost)
// -> LDS reduce -> A=[x_i|M] -> MFMA -> epilogue (+ optional t).
// Block = 256 threads = 16 nodes; wave w owns output h-tile [16w,16w+16).
template <bool RES, bool TOUT>
__global__ __launch_bounds__(256) void k_layer(
        int N, const unsigned* __restrict__ xinP,
        const unsigned* __restrict__ xresP, unsigned* __restrict__ xoutP,
        const int* __restrict__ rowptr, const unsigned short* __restrict__ csr,
        const unsigned short* __restrict__ pcsr,
        const float* __restrict__ ssinv,
        const unsigned short* __restrict__ WThl,   // [64 h][128 k] fp16
        const float* __restrict__ W3, const float* __restrict__ bias,
        const float* __restrict__ Wt, float* __restrict__ tvec) {
    __shared__ unsigned stage[16 * 1024];   // 64KB: node nd -> stage[nd*1024 + r*32 + dword]
    __shared__ unsigned Ald[16 * 64];       // 4KB A-tile, XOR-swizzled 16B groups
    __shared__ float Cld[16 * 64];          // 4KB C staging
    __shared__ int sdeg[16];
    __shared__ float sss[16];

    int t = threadIdx.x;
    int lane = t & 63;
    int wv = t >> 6;
    int n0 = blockIdx.x << 4;
    int kg = lane >> 4;

    // B-fragments for this wave's h-tile (16 VGPRs, whole kernel)
    int cb = (wv << 4) + (lane & 15);
    const uint4* wp = (const uint4*)WThl;
    uint4 b0 = wp[cb * 16 + kg + 0];
    uint4 b1 = wp[cb * 16 + kg + 4];
    uint4 b2 = wp[cb * 16 + kg + 8];
    uint4 b3 = wp[cb * 16 + kg + 12];

    const uint4* xin16 = (const uint4*)xinP;
    int sub = lane >> 3;     // which of 8 rows per DMA instruction this lane serves
    int lq = lane & 7;       // 16B slice within the 128B row
    int ndb = wv << 2;

    // per-node meta + padded-csr slot row
    int svp[4], degq[4], begq[4], endq[4];
    float ssq[4];
#pragma unroll
    for (int q = 0; q < 4; ++q) {
        int node = n0 + ndb + q;
        int nc = min(node, N - 1);
        svp[q] = (int)pcsr[((size_t)node << 6) + lane];
        int bg = __builtin_amdgcn_readfirstlane(rowptr[nc]);
        int en = __builtin_amdgcn_readfirstlane(rowptr[nc + 1]);
        begq[q] = bg; endq[q] = en;
        degq[q] = (node < N) ? (en - bg) : 0;
        ssq[q] = ssinv[nc];
    }

    // ---- issue 16 DMA instructions (chunk0: slots 0..31 of 4 nodes), zero VGPR cost ----
#pragma unroll
    for (int q = 0; q < 4; ++q) {
        int sv = svp[q];
        unsigned* sb = &stage[(ndb + q) << 10];
#pragma unroll
        for (int g = 0; g < 4; ++g) {
            int sidx = __shfl(sv, (g << 3) + sub, 64);
            const unsigned* gsrc = xinP + ((size_t)sidx << 5) + (lq << 2);
            dma16(gsrc, sb + (g << 8));   // rows 8g..8g+7, 1KB per instruction
        }
    }
    // x_i rows (register loads, in flight alongside DMA)
    uint4 xi[4];
#pragma unroll
    for (int q = 0; q < 4; ++q) {
        int node = n0 + ndb + q;
        xi[q] = make_uint4(0u, 0u, 0u, 0u);
        if (lane < 8 && node < N) xi[q] = xin16[(size_t)min(node, N - 1) * 8 + lane];
    }
    asm volatile("s_waitcnt vmcnt(0)" ::: "memory");
    __builtin_amdgcn_sched_barrier(0);

    // ---- reduce from LDS (+ register tails) ----
    uint4 mv[4];
#pragma unroll
    for (int q = 0; q < 4; ++q) {
        if (degq[q] <= 64) {
            const uint4* sp = (const uint4*)&stage[(ndb + q) << 10];
            uint4 d0 = sp[(sub) * 8 + lq];
            uint4 d1 = sp[(sub + 8) * 8 + lq];
            uint4 d2 = sp[(sub + 16) * 8 + lq];
            uint4 d3 = sp[(sub + 24) * 8 + lq];
            __half2 c0 = __hadd2(__hadd2(uh2(d0.x), uh2(d1.x)), __hadd2(uh2(d2.x), uh2(d3.x)));
            __half2 c1 = __hadd2(__hadd2(uh2(d0.y), uh2(d1.y)), __hadd2(uh2(d2.y), uh2(d3.y)));
            __half2 c2 = __hadd2(__hadd2(uh2(d0.z), uh2(d1.z)), __hadd2(uh2(d2.z), uh2(d3.z)));
            __half2 c3 = __hadd2(__hadd2(uh2(d0.w), uh2(d1.w)), __hadd2(uh2(d2.w), uh2(d3.w)));
            if (degq[q] > 32) chunk_acc(xin16, svp[q], 32, sub, lq, c0, c1, c2, c3);
#pragma unroll
            for (int m = 8; m <= 32; m <<= 1) {
                c0 = __hadd2(c0, uh2((unsigned)__shfl_xor((int)*(unsigned*)&c0, m, 64)));
                c1 = __hadd2(c1, uh2((unsigned)__shfl_xor((int)*(unsigned*)&c1, m, 64)));
                c2 = __hadd2(c2, uh2((unsigned)__shfl_xor((int)*(unsigned*)&c2, m, 64)));
                c3 = __hadd2(c3, uh2((unsigned)__shfl_xor((int)*(unsigned*)&c3, m, 64)));
            }
            float id = 1.f / (float)max(degq[q], 1);
            mv[q].x = packh(__half2float(__low2half(c0)) * id, __half2float(__high2half(c0)) * id);
            mv[q].y = packh(__half2float(__low2half(c1)) * id, __half2float(__high2half(c1)) * id);
            mv[q].z = packh(__half2float(__low2half(c2)) * id, __half2float(__high2half(c2)) * id);
            mv[q].w = packh(__half2float(__low2half(c3)) * id, __half2float(__high2half(c3)) * id);
        } else {
            float a[8];
            slow_gather(xin16, csr, begq[q], endq[q], N, lane, sub, lq, a);
            float id = 1.f / (float)degq[q];
            mv[q].x = packh(a[0] * id, a[1] * id);
            mv[q].y = packh(a[2] * id, a[3] * id);
            mv[q].z = packh(a[4] * id, a[5] * id);
            mv[q].w = packh(a[6] * id, a[7] * id);
        }
    }

    // ---- LDS A-tile writes ----
#pragma unroll
    for (int q = 0; q < 4; ++q) {
        int nd = ndb + q;
        if (lane < 8) {
            int gx = lane ^ (nd & 7);
            int gm = (8 + lane) ^ (nd & 7);
            ((uint4*)Ald)[nd * 16 + gx] = xi[q];
            ((uint4*)Ald)[nd * 16 + gm] = mv[q];
        }
        if (lane == 0) { sdeg[nd] = degq[q]; sss[nd] = ssq[q]; }
    }
    __syncthreads();

    // ---- MFMA: C[16 nodes][16 h] = A[16][128] @ B[128][16] ----
    int r = lane & 15;
    const uint4* ap = (const uint4*)Ald;
    int rx = (r & 7);
    uint4 fa0 = ap[r * 16 + ((0 + kg) ^ rx)];
    uint4 fa1 = ap[r * 16 + ((4 + kg) ^ rx)];
    uint4 fa2 = ap[r * 16 + ((8 + kg) ^ rx)];
    uint4 fa3 = ap[r * 16 + ((12 + kg) ^ rx)];
    f32x4 acc = {0.f, 0.f, 0.f, 0.f};
    acc = __builtin_amdgcn_mfma_f32_16x16x32_f16(u4h(fa0), u4h(b0), acc, 0, 0, 0);
    acc = __builtin_amdgcn_mfma_f32_16x16x32_f16(u4h(fa1), u4h(b1), acc, 0, 0, 0);
    acc = __builtin_amdgcn_mfma_f32_16x16x32_f16(u4h(fa2), u4h(b2), acc, 0, 0, 0);
    acc = __builtin_amdgcn_mfma_f32_16x16x32_f16(u4h(fa3), u4h(b3), acc, 0, 0, 0);
#pragma unroll
    for (int reg = 0; reg < 4; ++reg)
        Cld[(kg * 4 + reg) * 64 + (wv << 4) + r] = acc[reg];
    __syncthreads();

    // ---- epilogue: thread t -> node t>>4, dword cols (t&15) and (t&15)+16 ----
    int nd = t >> 4;
    int node = n0 + nd;
    if (node < N) {
        int dg = sdeg[nd];
        float ss = sss[nd];
        float tp = 0.f;
#pragma unroll
        for (int jj = 0; jj < 2; ++jj) {
            int j = (t & 15) + jj * 16;
            float y0 = Cld[nd * 64 + 2 * j];
            float y1 = Cld[nd * 64 + 2 * j + 1];
            float2 w3 = ((const float2*)W3)[j];
            float2 bb = ((const float2*)bias)[j];
            y0 += ss * w3.x + bb.x;
            y1 += ss * w3.y + bb.y;
            if (dg == 0) { y0 = 0.f; y1 = 0.f; }
            if (RES) {
                unsigned rw = xresP[(size_t)node * 32 + j];
                y0 += h_lo(rw);
                y1 += h_hi(rw);
            }
            y0 = (y0 > 0.f) ? y0 : NEG_SLOPE * y0;
            y1 = (y1 > 0.f) ? y1 : NEG_SLOPE * y1;
            if (TOUT) {
                float2 wt = ((const float2*)Wt)[j];
                tp += y0 * wt.x + y1 * wt.y;
            }
            xoutP[(size_t)node * 32 + j] = packh(y0, y1);
        }
        if (TOUT) {
            tp += __shfl_xor(tp, 1, 64);
            tp += __shfl_xor(tp, 2, 64);
            tp += __shfl_xor(tp, 4, 64);
            tp += __shfl_xor(tp, 8, 64);
            if ((t & 15) == 0) tvec[node] = tp;
        }
    }
}

// conv_out + residual x; branch-free t-gather via pcsr (t[N]=0 sentinel)
__global__ void k_out(int N, const unsigned* __restrict__ xAP, const float* __restrict__ x0,
                      const int* __restrict__ rowptr, const unsigned short* __restrict__ csr,
                      const unsigned short* __restrict__ pcsr,
                      const float* __restrict__ ssinv, const float* __restrict__ t,
                      const float* __restrict__ W_out, const float* __restrict__ b_out,
                      float* __restrict__ out) {
    int wid = blockIdx.x * (blockDim.x >> 6) + (threadIdx.x >> 6);
    int lane = threadIdx.x & 63;
    if (wid >= N) return;
    int beg = rowptr[wid], end = rowptr[wid + 1];
    int deg = end - beg;
    float s;
    if (deg <= 64) {
        int sl = (int)pcsr[((size_t)wid << 6) + lane];
        s = t[sl];
    } else {
        s = 0.f;
        for (int e = beg + lane; e < end; e += 64) s += t[csr[e]];
    }
    unsigned xw = xAP[(size_t)wid * 32 + (lane >> 1)];
    float xf = (lane & 1) ? h_hi(xw) : h_lo(xw);
    float p = xf * (W_out[lane] - W_out[64 + lane]);
    for (int m = 32; m >= 1; m >>= 1) {
        s += __shfl_xor(s, m, 64);
        p += __shfl_xor(p, m, 64);
    }
    float invd = 1.f / (float)max(deg, 1);
    float y = p + s * invd + ssinv[wid] * W_out[128] + b_out[0];
    if (deg == 0) y = 0.f;
    if (lane == 0) out[wid] = y + x0[wid];
}

static inline size_t align16(size_t x) { return (x + 15) & ~(size_t)15; }

extern "C" void kernel_launch(void* const* d_in, const int* in_sizes, int n_in,
                              void* d_out, int out_size, void* d_ws, size_t ws_size,
                              hipStream_t stream) {
    const float* x0    = (const float*)d_in[0];
    const int*   ei    = (const int*)d_in[1];
    const float* W_in  = (const float*)d_in[2];
    const float* b_in  = (const float*)d_in[3];
    const float* W_mid = (const float*)d_in[4];
    const float* b_mid = (const float*)d_in[5];
    const float* W_out = (const float*)d_in[6];
    const float* b_out = (const float*)d_in[7];
    float* out = (float*)d_out;

    const int N = in_sizes[0];
    const int E = in_sizes[1] / 2;
    const int L = in_sizes[4] / (129 * 64);
    const int NB = (N + 127) >> 7;
    const int* src = ei;
    const int* dst = ei + E;

    char* p = (char*)d_ws;
    unsigned short* WTh = (unsigned short*)p; p += align16((size_t)L * 64 * 128 * 2);
    unsigned* xAP = (unsigned*)p; p += align16((size_t)(N + 1) * 32 * 4);
    unsigned* xBP = (unsigned*)p; p += align16((size_t)(N + 1) * 32 * 4);
    unsigned* bucketed = (unsigned*)p; p += align16((size_t)NB * CAPB * 4);
    unsigned short* csr = (unsigned short*)p; p += align16((size_t)E * 2);
    unsigned short* pcsr = (unsigned short*)p; p += align16((size_t)NB * 8192 * 2);
    int* gcur          = (int*)p; p += align16((size_t)(NB + 1) * 4);
    int* rowptr        = (int*)p; p += align16((size_t)(N + 1) * 4);
    float* ssinv       = (float*)p; p += align16((size_t)N * 4);
    float* t           = (float*)p; p += align16((size_t)(N + 1) * 4);

    const int nb_w4 = (N + 3) / 4;
    const int nb_bkt = (E + EPB - 1) / EPB;
    const int ptotal = L * 64 * 128;
    const int nb_lay = (N + 15) / 16;

    k_setup<<<(ptotal + 255) / 256, 256, 0, stream>>>(ptotal, W_mid, WTh, NB, gcur, N, xAP, xBP, t);
    k_bucket<<<nb_bkt, 1024, 0, stream>>>(E, src, dst, gcur, bucketed, NB);
    k_csr<<<NB, 512, 0, stream>>>(N, NB, bucketed, gcur, csr, pcsr, rowptr, ssinv,
                                  x0, W_in, b_in, xAP);

    for (int l = 0; l < L / 2; ++l) {
        bool last = (l == L / 2 - 1);
        const unsigned short* Wa = WTh + (size_t)(2 * l) * 64 * 128;
        const unsigned short* Wb = WTh + (size_t)(2 * l + 1) * 64 * 128;
        const float* W3a = W_mid + (size_t)(2 * l) * 129 * 64 + 128 * 64;
        const float* W3b = W_mid + (size_t)(2 * l + 1) * 129 * 64 + 128 * 64;

        // x1 = leaky(conv(x2)) : xAP -> xBP
        k_layer<false, false><<<nb_lay, 256, 0, stream>>>(
            N, xAP, nullptr, xBP, rowptr, csr, pcsr, ssinv,
            Wa, W3a, b_mid + (size_t)(2 * l) * HDIM, nullptr, nullptr);
        // x2 = leaky(conv(x1) + x2) : xBP (+xAP) -> xAP   [+ t on last]
        if (!last) {
            k_layer<true, false><<<nb_lay, 256, 0, stream>>>(
                N, xBP, xAP, xAP, rowptr, csr, pcsr, ssinv,
                Wb, W3b, b_mid + (size_t)(2 * l + 1) * HDIM, nullptr, nullptr);
        } else {
            k_layer<true, true><<<nb_lay, 256, 0, stream>>>(
                N, xBP, xAP, xAP, rowptr, csr, pcsr, ssinv,
                Wb, W3b, b_mid + (size_t)(2 * l + 1) * HDIM, W_out + 64, t);
        }
    }

    k_out<<<nb_w4, 256, 0, stream>>>(N, xAP, x0, rowptr, csr, pcsr, ssinv, t,
                                     W_out, b_out, out);
}

// Round 16
// 234.422 us; speedup vs baseline: 1.4931x; 1.4931x over previous
//
#include <hip/hip_runtime.h>
#include <hip/hip_fp16.h>

#define HDIM 64
#define NEG_SLOPE 0.01f
#define CAPB 8192      // bucketed[] region per 128-node bucket
#define BCAP 6144      // LDS staging capacity in k_csr
#define EPB  4096      // edges per k_bucket block

typedef _Float16 half8 __attribute__((ext_vector_type(8)));
typedef float f32x4 __attribute__((ext_vector_type(4)));

static __device__ __forceinline__ float h_lo(unsigned d) {
    return __half2float(__ushort_as_half((unsigned short)(d & 0xffffu)));
}
static __device__ __forceinline__ float h_hi(unsigned d) {
    return __half2float(__ushort_as_half((unsigned short)(d >> 16)));
}
static __device__ __forceinline__ unsigned packh(float a, float b) {
    unsigned short ra = __half_as_ushort(__float2half(a));
    unsigned short rb = __half_as_ushort(__float2half(b));
    return ((unsigned)rb << 16) | (unsigned)ra;
}
static __device__ __forceinline__ half8 u4h(uint4 v) {
    union { uint4 u; half8 h; } x; x.u = v; return x.h;
}
static __device__ __forceinline__ __half2 uh2(unsigned u) {
    union { unsigned u; __half2 h; } x; x.u = u; return x.h;
}

// merged setup: WTh prep + gcur init + sentinel rows (features and t)
__global__ void k_setup(int ptotal, const float* __restrict__ W_mid,
                        unsigned short* __restrict__ WTh,
                        int NB, int* gcur, int N, unsigned* xAP, unsigned* xBP,
                        float* tvec) {
    int i = blockIdx.x * blockDim.x + threadIdx.x;
    if (i < ptotal) {
        int l = i >> 13;
        int rem = i & 8191;
        int h = rem >> 7;
        int k = rem & 127;
        const float* W = W_mid + (size_t)l * 129 * 64;
        float v = W[k * 64 + h] - ((k < 64) ? W[(64 + k) * 64 + h] : 0.f);
        WTh[i] = __half_as_ushort(__float2half(v));
    }
    if (i < NB) gcur[i] = i * CAPB;
    if (i < 32) xAP[(size_t)N * 32 + i] = 0u;
    else if (i < 64) xBP[(size_t)N * 32 + (i - 32)] = 0u;
    else if (i == 64) tvec[N] = 0.f;
}

// Phase 1: counting-sort bucketing. One atomic pass (rank+count), LDS scan,
// in-LDS sort by bucket, coalesced run-wise write-out.
__global__ __launch_bounds__(1024) void k_bucket(
        int E, const int* __restrict__ src, const int* __restrict__ dst,
        int* gcur, unsigned* __restrict__ bucketed, int NB) {
    __shared__ int lh[512];       // per-bucket counts (preserved)
    __shared__ int sd[512];       // inclusive scan
    __shared__ int lbase[512];    // global base per bucket
    __shared__ unsigned sorted[EPB];
    int t = threadIdx.x;
    int e0 = blockIdx.x * EPB;
    if (t < 512) lh[t] = 0;
    __syncthreads();
    int dv[4], sv[4], rv[4];
#pragma unroll
    for (int k = 0; k < 4; ++k) {
        int e = e0 + k * 1024 + t;
        dv[k] = (e < E) ? dst[e] : -1;
        sv[k] = (e < E) ? src[e] : 0;
    }
#pragma unroll
    for (int k = 0; k < 4; ++k)
        rv[k] = (dv[k] >= 0) ? atomicAdd(&lh[((unsigned)dv[k]) >> 7], 1) : 0;
    __syncthreads();
    int c = (t < 512) ? lh[t] : 0;
    if (t < 512) {
        lbase[t] = (c > 0) ? atomicAdd(&gcur[t], c) : 0;
        sd[t] = c;
    }
    __syncthreads();
    int x = c;
    for (int s = 1; s < 512; s <<= 1) {
        int p = (t < 512 && t >= s) ? sd[t - s] : 0;
        __syncthreads();
        if (t < 512) { x += p; sd[t] = x; }
        __syncthreads();
    }
    // place into bucket-sorted LDS order: idx = excl(b) + rank
#pragma unroll
    for (int k = 0; k < 4; ++k) {
        if (dv[k] >= 0) {
            int b = ((unsigned)dv[k]) >> 7;
            sorted[sd[b] - lh[b] + rv[k]] = ((unsigned)dv[k] << 16) | (unsigned)sv[k];
        }
    }
    __syncthreads();
    int ntot = sd[511];
    for (int i = t; i < ntot; i += 1024) {
        unsigned w = sorted[i];
        int b = (int)(w >> 23);                    // dst>>7
        int pos = lbase[b] + (i - (sd[b] - lh[b]));
        if (pos < (b + 1) * CAPB) bucketed[pos] = w;
    }
}

// Phase 2: per bucket, internal gstart scan + LDS hist/scan -> rowptr/ssinv,
// exact csr, LDS-built padded pcsr (coalesced dump), AND fused conv_in.
__global__ __launch_bounds__(512) void k_csr(
        int N, int NB, const unsigned* __restrict__ bucketed, const int* __restrict__ gcur,
        unsigned short* __restrict__ csr, unsigned short* __restrict__ pcsr,
        int* __restrict__ rowptr, float* __restrict__ ssinv,
        const float* __restrict__ x0, const float* __restrict__ W_in,
        const float* __restrict__ b_in, unsigned* __restrict__ xAP) {
    __shared__ unsigned st[BCAP];                 // 24 KB
    __shared__ unsigned short lpcsr[128 * 64];    // 16 KB node-major slots
    __shared__ int hist[128], cur[128], excl[128], sgp[128], sdegl[128];
    __shared__ float sssl[128];
    __shared__ int gsd[512];
    int b = blockIdx.x, t = threadIdx.x;
    int n0 = b << 7;
    int nn = min(128, N - n0);
    // internal exclusive scan of bucket counts -> base for this block
    int cc = (t < NB) ? min(gcur[t] - t * CAPB, CAPB) : 0;
    gsd[t] = cc;
    __syncthreads();
    int xs = cc;
    for (int s = 1; s < 512; s <<= 1) {
        int p = (t >= s) ? gsd[t - s] : 0;
        __syncthreads();
        xs += p;
        gsd[t] = xs;
        __syncthreads();
    }
    int cnt = min(gcur[b] - b * CAPB, CAPB);
    int base = gsd[b] - cnt;
    if (b == NB - 1 && t == 0) rowptr[N] = gsd[NB - 1];
    if (t < 128) { hist[t] = 0; sgp[t] = 0; }
    unsigned sent = ((unsigned)N << 16) | (unsigned)N;
    for (int i = t; i < 4096; i += 512) ((unsigned*)lpcsr)[i] = sent;
    __syncthreads();
    bool single = (cnt <= BCAP);
    for (int off = 0; off < cnt; off += BCAP) {
        int bs = min(BCAP, cnt - off);
        for (int i = t; i < bs; i += 512) {
            unsigned w = bucketed[b * CAPB + off + i];
            if (single) st[i] = w;
            int d = (int)(w >> 16);
            int s = (int)(w & 0xffffu);
            int dl = d - n0;
            atomicAdd(&hist[dl], 1);
            atomicAdd(&sgp[dl], ((s < d) ? 1024 : 0) + ((s == d) ? 1 : 0));
        }
    }
    __syncthreads();
    int deg_t = (t < 128) ? hist[t] : 0;
    int x = deg_t;
    for (int s = 1; s < 128; s <<= 1) {
        int p = (t < 128 && t >= s) ? hist[t - s] : 0;
        __syncthreads();
        if (t < 128) { x += p; hist[t] = x; }
        __syncthreads();
    }
    if (t < 128) {
        int ex = hist[t] - deg_t;
        excl[t] = ex;
        cur[t] = ex;
        sdegl[t] = deg_t;
        float ssv = 0.f;
        if (t < nn) {
            rowptr[n0 + t] = base + ex;
            int sg = sgp[t];
            int lt = sg >> 10, eq = sg & 1023;
            float ss = (float)(deg_t - eq - 2 * lt);
            ssv = (deg_t > 0) ? ss / (float)deg_t : 0.f;
            ssinv[n0 + t] = ssv;
        }
        sssl[t] = ssv;
    }
    __syncthreads();
    for (int off = 0; off < cnt; off += BCAP) {
        int bs = min(BCAP, cnt - off);
        if (!single) {
            for (int i = t; i < bs; i += 512) st[i] = bucketed[b * CAPB + off + i];
            __syncthreads();
        }
        for (int i = t; i < bs; i += 512) {
            unsigned w = st[i];
            int dl = (int)(w >> 16) - n0;
            unsigned short sval = (unsigned short)(w & 0xffffu);
            int p = atomicAdd(&cur[dl], 1);
            csr[base + p] = sval;
            int r = p - excl[dl];
            if (r < 64) lpcsr[(dl << 6) + r] = sval;
        }
        if (!single) __syncthreads();
    }
    __syncthreads();
    // coalesced dump of node-major slots -> global pcsr (16 KB contiguous)
    {
        uint4* gp = (uint4*)(pcsr + ((size_t)b << 13));
        const uint4* lp = (const uint4*)lpcsr;
        for (int i = t; i < 1024; i += 512) gp[i] = lp[i];
    }
    // fused conv_in: 8 waves x 16 nodes; x [N,1] fp32 -> packed fp16 row
    int lane = t & 63;
    int wvq = t >> 6;
    float w1 = W_in[lane], w2 = W_in[64 + lane], w3 = W_in[128 + lane];
    float bi = b_in[lane];
    for (int i = 0; i < 16; ++i) {
        int nd = (wvq << 4) + i;
        int node = n0 + nd;
        if (node >= N) break;
        int deg = sdegl[nd];
        float s;
        if (deg <= 64) {
            int sl = (int)lpcsr[(nd << 6) + lane];
            s = (sl < N) ? x0[sl] : 0.f;
        } else {
            s = 0.f;
            int bg = base + excl[nd], en = bg + deg;
            for (int e = bg + lane; e < en; e += 64) s += x0[csr[e]];
        }
        for (int m = 32; m >= 1; m >>= 1) s += __shfl_xor(s, m, 64);
        float invd = 1.f / (float)max(deg, 1);
        float mean = s * invd;
        float xi = x0[node];
        float y = xi * (w1 - w2) + mean * w2 + sssl[nd] * w3 + bi;
        if (deg == 0) y = 0.f;
        float ylo = __shfl(y, (2 * lane) & 63, 64);
        float yhi = __shfl(y, (2 * lane + 1) & 63, 64);
        if (lane < 32) xAP[(size_t)node * 32 + lane] = packh(ylo, yhi);
    }
}

// one 32-slot chunk: 4 shfl + 4 unguarded uint4 loads, fp16 packed accumulate
static __device__ __forceinline__ void chunk_acc(
        const uint4* __restrict__ xin16, int sv, int base, int sub, int lq,
        __half2& c0, __half2& c1, __half2& c2, __half2& c3) {
    int s0 = __shfl(sv, base + sub, 64);
    int s1 = __shfl(sv, base + 8 + sub, 64);
    int s2 = __shfl(sv, base + 16 + sub, 64);
    int s3 = __shfl(sv, base + 24 + sub, 64);
    uint4 d0 = xin16[(size_t)s0 * 8 + lq];
    uint4 d1 = xin16[(size_t)s1 * 8 + lq];
    uint4 d2 = xin16[(size_t)s2 * 8 + lq];
    uint4 d3 = xin16[(size_t)s3 * 8 + lq];
    c0 = __hadd2(c0, __hadd2(__hadd2(uh2(d0.x), uh2(d1.x)), __hadd2(uh2(d2.x), uh2(d3.x))));
    c1 = __hadd2(c1, __hadd2(__hadd2(uh2(d0.y), uh2(d1.y)), __hadd2(uh2(d2.y), uh2(d3.y))));
    c2 = __hadd2(c2, __hadd2(__hadd2(uh2(d0.z), uh2(d1.z)), __hadd2(uh2(d2.z), uh2(d3.z))));
    c3 = __hadd2(c3, __hadd2(__hadd2(uh2(d0.w), uh2(d1.w)), __hadd2(uh2(d2.w), uh2(d3.w))));
}

// rare exact-csr gather (deg>64), f32 accumulate, reduced into a[8]
static __device__ __forceinline__ void slow_gather(
        const uint4* __restrict__ xin16, const unsigned short* __restrict__ csr,
        int beg, int end, int N, int lane, int sub, int lq, float* a) {
#pragma unroll
    for (int j = 0; j < 8; ++j) a[j] = 0.f;
    for (int tb = beg; tb < end; tb += 64) {
        int cnt = min(64, end - tb);
        int sv = (lane < cnt) ? (int)csr[tb + lane] : N;
        int ng = (cnt + 7) >> 3;
        for (int g = 0; g < ng; ++g) {
            int si = __shfl(sv, (g << 3) + sub, 64);
            uint4 d = xin16[(size_t)si * 8 + lq];
            a[0] += h_lo(d.x); a[1] += h_hi(d.x);
            a[2] += h_lo(d.y); a[3] += h_hi(d.y);
            a[4] += h_lo(d.z); a[5] += h_hi(d.z);
            a[6] += h_lo(d.w); a[7] += h_hi(d.w);
        }
    }
#pragma unroll
    for (int m = 8; m <= 32; m <<= 1) {
#pragma unroll
        for (int j = 0; j < 8; ++j) a[j] += __shfl_xor(a[j], m, 64);
    }
}

// Fused layer: chunk-adaptive paired gather -> LDS A=[x_i|M] -> MFMA -> epilogue (+ optional t).
// Block = 256 threads = 16 nodes; wave w owns output h-tile [16w,16w+16).
template <bool RES, bool TOUT>
__global__ __launch_bounds__(256) void k_layer(
        int N, const unsigned* __restrict__ xinP,
        const unsigned* __restrict__ xresP, unsigned* __restrict__ xoutP,
        const int* __restrict__ rowptr, const unsigned short* __restrict__ csr,
        const unsigned short* __restrict__ pcsr,
        const float* __restrict__ ssinv,
        const unsigned short* __restrict__ WThl,   // [64 h][128 k] fp16
        const float* __restrict__ W3, const float* __restrict__ bias,
        const float* __restrict__ Wt, float* __restrict__ tvec) {
    __shared__ unsigned Ald[16 * 64];   // 16 nodes x 64 dwords (128 f16), XOR-swizzled 16B groups
    __shared__ float Cld[16 * 64];
    __shared__ int sdeg[16];
    __shared__ float sss[16];

    int t = threadIdx.x;
    int lane = t & 63;
    int wv = t >> 6;
    int n0 = blockIdx.x << 4;
    int kg = lane >> 4;

    // B-fragments for this wave's h-tile (16 VGPRs, whole kernel)
    int cb = (wv << 4) + (lane & 15);
    const uint4* wp = (const uint4*)WThl;
    uint4 b0 = wp[cb * 16 + kg + 0];
    uint4 b1 = wp[cb * 16 + kg + 4];
    uint4 b2 = wp[cb * 16 + kg + 8];
    uint4 b3 = wp[cb * 16 + kg + 12];

    const uint4* xin16 = (const uint4*)xinP;
    int sub = lane >> 3;     // which of 8 rows in a group this lane serves
    int lq = lane & 7;       // 16B slice within the 128B row
    int ndb = wv << 2;

    // preload padded-csr rows for all 4 nodes (rows exist through NB*128; sentinel-filled)
    int svp[4];
#pragma unroll
    for (int q = 0; q < 4; ++q)
        svp[q] = (int)pcsr[((size_t)(n0 + ndb + q) << 6) + lane];

    // ---- gather phase: 2 nodes jointly per step; chunk-adaptive (skip all-sentinel chunks) ----
#pragma unroll
    for (int qp = 0; qp < 2; ++qp) {
        int ndA = ndb + (qp << 1);
        int ndB = ndA + 1;
        int nodeA = n0 + ndA, nodeB = n0 + ndB;
        int ncA = min(nodeA, N - 1), ncB = min(nodeB, N - 1);
        int begA = __builtin_amdgcn_readfirstlane(rowptr[ncA]);
        int endA = __builtin_amdgcn_readfirstlane(rowptr[ncA + 1]);
        int begB = __builtin_amdgcn_readfirstlane(rowptr[ncB]);
        int endB = __builtin_amdgcn_readfirstlane(rowptr[ncB + 1]);
        int degA = (nodeA < N) ? (endA - begA) : 0;
        int degB = (nodeB < N) ? (endB - begB) : 0;
        float ssvA = ssinv[ncA];
        float ssvB = ssinv[ncB];
        uint4 xiA = make_uint4(0u, 0u, 0u, 0u), xiB = make_uint4(0u, 0u, 0u, 0u);
        if (lane < 8) {
            if (nodeA < N) xiA = xin16[(size_t)ncA * 8 + lane];
            if (nodeB < N) xiB = xin16[(size_t)ncB * 8 + lane];
        }
        uint4 mvA, mvB;
        if (max(degA, degB) <= 64) {
            __half2 z = uh2(0u);
            __half2 cA0 = z, cA1 = z, cA2 = z, cA3 = z;
            __half2 cB0 = z, cB1 = z, cB2 = z, cB3 = z;
            int svA = svp[qp << 1], svB = svp[(qp << 1) + 1];
            // chunk 0 (slots 0..31) for both nodes: 8 loads in flight
            chunk_acc(xin16, svA, 0, sub, lq, cA0, cA1, cA2, cA3);
            chunk_acc(xin16, svB, 0, sub, lq, cB0, cB1, cB2, cB3);
            // tail chunks only when needed (wave-uniform)
            if (degA > 32) chunk_acc(xin16, svA, 32, sub, lq, cA0, cA1, cA2, cA3);
            if (degB > 32) chunk_acc(xin16, svB, 32, sub, lq, cB0, cB1, cB2, cB3);
            // cross-lane packed reduce over the 8 sub-groups
#pragma unroll
            for (int m = 8; m <= 32; m <<= 1) {
                cA0 = __hadd2(cA0, uh2((unsigned)__shfl_xor((int)*(unsigned*)&cA0, m, 64)));
                cA1 = __hadd2(cA1, uh2((unsigned)__shfl_xor((int)*(unsigned*)&cA1, m, 64)));
                cA2 = __hadd2(cA2, uh2((unsigned)__shfl_xor((int)*(unsigned*)&cA2, m, 64)));
                cA3 = __hadd2(cA3, uh2((unsigned)__shfl_xor((int)*(unsigned*)&cA3, m, 64)));
                cB0 = __hadd2(cB0, uh2((unsigned)__shfl_xor((int)*(unsigned*)&cB0, m, 64)));
                cB1 = __hadd2(cB1, uh2((unsigned)__shfl_xor((int)*(unsigned*)&cB1, m, 64)));
                cB2 = __hadd2(cB2, uh2((unsigned)__shfl_xor((int)*(unsigned*)&cB2, m, 64)));
                cB3 = __hadd2(cB3, uh2((unsigned)__shfl_xor((int)*(unsigned*)&cB3, m, 64)));
            }
            float idA = 1.f / (float)max(degA, 1);
            float idB = 1.f / (float)max(degB, 1);
            mvA.x = packh(__half2float(__low2half(cA0)) * idA, __half2float(__high2half(cA0)) * idA);
            mvA.y = packh(__half2float(__low2half(cA1)) * idA, __half2float(__high2half(cA1)) * idA);
            mvA.z = packh(__half2float(__low2half(cA2)) * idA, __half2float(__high2half(cA2)) * idA);
            mvA.w = packh(__half2float(__low2half(cA3)) * idA, __half2float(__high2half(cA3)) * idA);
            mvB.x = packh(__half2float(__low2half(cB0)) * idB, __half2float(__high2half(cB0)) * idB);
            mvB.y = packh(__half2float(__low2half(cB1)) * idB, __half2float(__high2half(cB1)) * idB);
            mvB.z = packh(__half2float(__low2half(cB2)) * idB, __half2float(__high2half(cB2)) * idB);
            mvB.w = packh(__half2float(__low2half(cB3)) * idB, __half2float(__high2half(cB3)) * idB);
        } else {
            float aA[8], aB[8];
            slow_gather(xin16, csr, begA, endA, N, lane, sub, lq, aA);
            slow_gather(xin16, csr, begB, endB, N, lane, sub, lq, aB);
            float idA = 1.f / (float)max(degA, 1);
            float idB = 1.f / (float)max(degB, 1);
            mvA.x = packh(aA[0] * idA, aA[1] * idA);
            mvA.y = packh(aA[2] * idA, aA[3] * idA);
            mvA.z = packh(aA[4] * idA, aA[5] * idA);
            mvA.w = packh(aA[6] * idA, aA[7] * idA);
            mvB.x = packh(aB[0] * idB, aB[1] * idB);
            mvB.y = packh(aB[2] * idB, aB[3] * idB);
            mvB.z = packh(aB[4] * idB, aB[5] * idB);
            mvB.w = packh(aB[6] * idB, aB[7] * idB);
        }
        if (lane < 8) {
            int gxA = lane ^ (ndA & 7), gmA = (8 + lane) ^ (ndA & 7);
            int gxB = lane ^ (ndB & 7), gmB = (8 + lane) ^ (ndB & 7);
            ((uint4*)Ald)[ndA * 16 + gxA] = xiA;
            ((uint4*)Ald)[ndA * 16 + gmA] = mvA;
            ((uint4*)Ald)[ndB * 16 + gxB] = xiB;
            ((uint4*)Ald)[ndB * 16 + gmB] = mvB;
        }
        if (lane == 0) {
            sdeg[ndA] = degA; sss[ndA] = ssvA;
            sdeg[ndB] = degB; sss[ndB] = ssvB;
        }
    }
    __syncthreads();

    // ---- MFMA: C[16 nodes][16 h] = A[16][128] @ B[128][16] ----
    int r = lane & 15;
    const uint4* ap = (const uint4*)Ald;
    int rx = (r & 7);
    uint4 fa0 = ap[r * 16 + ((0 + kg) ^ rx)];
    uint4 fa1 = ap[r * 16 + ((4 + kg) ^ rx)];
    uint4 fa2 = ap[r * 16 + ((8 + kg) ^ rx)];
    uint4 fa3 = ap[r * 16 + ((12 + kg) ^ rx)];
    f32x4 acc = {0.f, 0.f, 0.f, 0.f};
    acc = __builtin_amdgcn_mfma_f32_16x16x32_f16(u4h(fa0), u4h(b0), acc, 0, 0, 0);
    acc = __builtin_amdgcn_mfma_f32_16x16x32_f16(u4h(fa1), u4h(b1), acc, 0, 0, 0);
    acc = __builtin_amdgcn_mfma_f32_16x16x32_f16(u4h(fa2), u4h(b2), acc, 0, 0, 0);
    acc = __builtin_amdgcn_mfma_f32_16x16x32_f16(u4h(fa3), u4h(b3), acc, 0, 0, 0);
#pragma unroll
    for (int reg = 0; reg < 4; ++reg)
        Cld[(kg * 4 + reg) * 64 + (wv << 4) + r] = acc[reg];
    __syncthreads();

    // ---- epilogue: thread t -> node t>>4, dword cols (t&15) and (t&15)+16 ----
    int nd = t >> 4;
    int node = n0 + nd;
    if (node < N) {
        int dg = sdeg[nd];
        float ss = sss[nd];
        float tp = 0.f;
#pragma unroll
        for (int jj = 0; jj < 2; ++jj) {
            int j = (t & 15) + jj * 16;
            float y0 = Cld[nd * 64 + 2 * j];
            float y1 = Cld[nd * 64 + 2 * j + 1];
            float2 w3 = ((const float2*)W3)[j];
            float2 bb = ((const float2*)bias)[j];
            y0 += ss * w3.x + bb.x;
            y1 += ss * w3.y + bb.y;
            if (dg == 0) { y0 = 0.f; y1 = 0.f; }
            if (RES) {
                unsigned rw = xresP[(size_t)node * 32 + j];
                y0 += h_lo(rw);
                y1 += h_hi(rw);
            }
            y0 = (y0 > 0.f) ? y0 : NEG_SLOPE * y0;
            y1 = (y1 > 0.f) ? y1 : NEG_SLOPE * y1;
            if (TOUT) {
                float2 wt = ((const float2*)Wt)[j];
                tp += y0 * wt.x + y1 * wt.y;
            }
            xoutP[(size_t)node * 32 + j] = packh(y0, y1);
        }
        if (TOUT) {
            tp += __shfl_xor(tp, 1, 64);
            tp += __shfl_xor(tp, 2, 64);
            tp += __shfl_xor(tp, 4, 64);
            tp += __shfl_xor(tp, 8, 64);
            if ((t & 15) == 0) tvec[node] = tp;
        }
    }
}

// conv_out + residual x; branch-free t-gather via pcsr (t[N]=0 sentinel)
__global__ void k_out(int N, const unsigned* __restrict__ xAP, const float* __restrict__ x0,
                      const int* __restrict__ rowptr, const unsigned short* __restrict__ csr,
                      const unsigned short* __restrict__ pcsr,
                      const float* __restrict__ ssinv, const float* __restrict__ t,
                      const float* __restrict__ W_out, const float* __restrict__ b_out,
                      float* __restrict__ out) {
    int wid = blockIdx.x * (blockDim.x >> 6) + (threadIdx.x >> 6);
    int lane = threadIdx.x & 63;
    if (wid >= N) return;
    int beg = rowptr[wid], end = rowptr[wid + 1];
    int deg = end - beg;
    float s;
    if (deg <= 64) {
        int sl = (int)pcsr[((size_t)wid << 6) + lane];
        s = t[sl];
    } else {
        s = 0.f;
        for (int e = beg + lane; e < end; e += 64) s += t[csr[e]];
    }
    unsigned xw = xAP[(size_t)wid * 32 + (lane >> 1)];
    float xf = (lane & 1) ? h_hi(xw) : h_lo(xw);
    float p = xf * (W_out[lane] - W_out[64 + lane]);
    for (int m = 32; m >= 1; m >>= 1) {
        s += __shfl_xor(s, m, 64);
        p += __shfl_xor(p, m, 64);
    }
    float invd = 1.f / (float)max(deg, 1);
    float y = p + s * invd + ssinv[wid] * W_out[128] + b_out[0];
    if (deg == 0) y = 0.f;
    if (lane == 0) out[wid] = y + x0[wid];
}

static inline size_t align16(size_t x) { return (x + 15) & ~(size_t)15; }

extern "C" void kernel_launch(void* const* d_in, const int* in_sizes, int n_in,
                              void* d_out, int out_size, void* d_ws, size_t ws_size,
                              hipStream_t stream) {
    const float* x0    = (const float*)d_in[0];
    const int*   ei    = (const int*)d_in[1];
    const float* W_in  = (const float*)d_in[2];
    const float* b_in  = (const float*)d_in[3];
    const float* W_mid = (const float*)d_in[4];
    const float* b_mid = (const float*)d_in[5];
    const float* W_out = (const float*)d_in[6];
    const float* b_out = (const float*)d_in[7];
    float* out = (float*)d_out;

    const int N = in_sizes[0];
    const int E = in_sizes[1] / 2;
    const int L = in_sizes[4] / (129 * 64);
    const int NB = (N + 127) >> 7;
    const int* src = ei;
    const int* dst = ei + E;

    char* p = (char*)d_ws;
    unsigned short* WTh = (unsigned short*)p; p += align16((size_t)L * 64 * 128 * 2);
    unsigned* xAP = (unsigned*)p; p += align16((size_t)(N + 1) * 32 * 4);
    unsigned* xBP = (unsigned*)p; p += align16((size_t)(N + 1) * 32 * 4);
    unsigned* bucketed = (unsigned*)p; p += align16((size_t)NB * CAPB * 4);
    unsigned short* csr = (unsigned short*)p; p += align16((size_t)E * 2);
    unsigned short* pcsr = (unsigned short*)p; p += align16((size_t)NB * 8192 * 2);
    int* gcur          = (int*)p; p += align16((size_t)(NB + 1) * 4);
    int* rowptr        = (int*)p; p += align16((size_t)(N + 1) * 4);
    float* ssinv       = (float*)p; p += align16((size_t)N * 4);
    float* t           = (float*)p; p += align16((size_t)(N + 1) * 4);

    const int nb_w4 = (N + 3) / 4;
    const int nb_bkt = (E + EPB - 1) / EPB;
    const int ptotal = L * 64 * 128;
    const int nb_lay = (N + 15) / 16;

    k_setup<<<(ptotal + 255) / 256, 256, 0, stream>>>(ptotal, W_mid, WTh, NB, gcur, N, xAP, xBP, t);
    k_bucket<<<nb_bkt, 1024, 0, stream>>>(E, src, dst, gcur, bucketed, NB);
    k_csr<<<NB, 512, 0, stream>>>(N, NB, bucketed, gcur, csr, pcsr, rowptr, ssinv,
                                  x0, W_in, b_in, xAP);

    for (int l = 0; l < L / 2; ++l) {
        bool last = (l == L / 2 - 1);
        const unsigned short* Wa = WTh + (size_t)(2 * l) * 64 * 128;
        const unsigned short* Wb = WTh + (size_t)(2 * l + 1) * 64 * 128;
        const float* W3a = W_mid + (size_t)(2 * l) * 129 * 64 + 128 * 64;
        const float* W3b = W_mid + (size_t)(2 * l + 1) * 129 * 64 + 128 * 64;

        // x1 = leaky(conv(x2)) : xAP -> xBP
        k_layer<false, false><<<nb_lay, 256, 0, stream>>>(
            N, xAP, nullptr, xBP, rowptr, csr, pcsr, ssinv,
            Wa, W3a, b_mid + (size_t)(2 * l) * HDIM, nullptr, nullptr);
        // x2 = leaky(conv(x1) + x2) : xBP (+xAP) -> xAP   [+ t on last]
        if (!last) {
            k_layer<true, false><<<nb_lay, 256, 0, stream>>>(
                N, xBP, xAP, xAP, rowptr, csr, pcsr, ssinv,
                Wb, W3b, b_mid + (size_t)(2 * l + 1) * HDIM, nullptr, nullptr);
        } else {
            k_layer<true, true><<<nb_lay, 256, 0, stream>>>(
                N, xBP, xAP, xAP, rowptr, csr, pcsr, ssinv,
                Wb, W3b, b_mid + (size_t)(2 * l + 1) * HDIM, W_out + 64, t);
        }
    }

    k_out<<<nb_w4, 256, 0, stream>>>(N, xAP, x0, rowptr, csr, pcsr, ssinv, t,
                                     W_out, b_out, out);
}